// Round 11
// baseline (23605.428 us; speedup 1.0000x reference)
//
#include <hip/hip_runtime.h>
#include <hip/hip_bf16.h>

typedef __hip_bfloat16 bf16;
typedef __bf16 bf16x8 __attribute__((ext_vector_type(8)));
typedef float f32x4 __attribute__((ext_vector_type(4)));

#define HID    1024
#define NSTEP  50
#define P      1032   // LDS pitch (bf16): r6-best (b128 A-reads; conflicts proven hidden)
#define SMEM_BYTES (64 * P * 2)   // X: [64 rows][P] bf16 staging (132,096 B)
#define FLAG_WORDS 12288          // 48KB flag area, carved from END of ws (in-bounds)

__device__ __forceinline__ f32x4 mfma16(bf16x8 a, bf16x8 b, f32x4 c) {
    return __builtin_amdgcn_mfma_f32_16x16x32_bf16(a, b, c, 0, 0, 0);
}

__device__ __forceinline__ float tanh_fast(float x) {
    float e = __expf(2.0f * x);
    return 1.0f - 2.0f / (e + 1.0f);   // saturates, no NaN for finite x
}

__device__ __forceinline__ bf16x8 ldcvt8(const float* __restrict__ p) {
    f32x4 lo = *(const f32x4*)p;
    f32x4 hi = *(const f32x4*)(p + 4);
    bf16x8 r;
    #pragma unroll
    for (int j = 0; j < 4; j++) { r[j] = (__bf16)lo[j]; r[4 + j] = (__bf16)hi[j]; }
    return r;
}

__device__ __forceinline__ unsigned bfbits(float f) {
    __hip_bfloat16 h = __float2bfloat16(f);
    unsigned short u; __builtin_memcpy(&u, &h, 2);
    return (unsigned)u;
}
__device__ __forceinline__ unsigned bfpack2(float lo, float hi) {
    return bfbits(lo) | (bfbits(hi) << 16);
}
__device__ __forceinline__ float bflo(unsigned u) { return __uint_as_float(u << 16); }
__device__ __forceinline__ float bfhi(unsigned u) { return __uint_as_float(u & 0xffff0000u); }
__device__ __forceinline__ bf16 bfraw(unsigned short u) {
    bf16 h; __builtin_memcpy(&h, &u, 2); return h;
}

// ---- pack f32 W[K][N] into bf16 MFMA B-fragment-linear layout ----
__global__ void pack_frag(const float* __restrict__ src, bf16* __restrict__ dst, int N) {
    int kb = blockIdx.x, nb = blockIdx.y, l = threadIdx.x;
    int lm = l & 15, lq = l >> 4;
    bf16x8 v;
    #pragma unroll
    for (int j = 0; j < 8; j++)
        v[j] = __float2bfloat16(src[(size_t)(kb * 32 + lq * 8 + j) * N + nb * 16 + lm]);
    *(bf16x8*)(dst + ((size_t)(kb * gridDim.y + nb) * 64 + l) * 8) = v;
}

__global__ void zero_flags(unsigned* __restrict__ f) {
    f[blockIdx.x * 1024 + threadIdx.x] = 0;
}

// ---- pairwise exchange primitives (system-scope: served past L2 -> no L2
// pollution/invalidation -> weights stay L2-resident; monotone flags so
// rocprof counter-replay without the zero-kernel sees pre-satisfied spins) ----
__device__ __forceinline__ void stx16(unsigned* dst, const unsigned (&v)[16]) {
    #pragma unroll
    for (int i = 0; i < 16; i++)
        __hip_atomic_store(dst + i, v[i], __ATOMIC_RELAXED, __HIP_MEMORY_SCOPE_SYSTEM);
}
__device__ __forceinline__ void ldx16(unsigned (&v)[16], unsigned* src) {
    #pragma unroll
    for (int i = 0; i < 16; i++)
        v[i] = __hip_atomic_load(src + i, __ATOMIC_RELAXED, __HIP_MEMORY_SCOPE_SYSTEM);
}
__device__ __forceinline__ void post_wave(unsigned* flag, unsigned val, int lane) {
    // RELEASE store: s_waitcnt drains this WAVE's prior stores (all 64 lanes)
    if (lane == 0)
        __hip_atomic_store(flag, val, __ATOMIC_RELEASE, __HIP_MEMORY_SCOPE_SYSTEM);
}
// BOUNDED spin: cooperative launch guarantees partner residency, so the bound
// never triggers in correct execution; if a logic bug exists it degrades to a
// wrong answer instead of a GPU hang (r10 lesson).
__device__ __forceinline__ void spin_wave(unsigned* flag, unsigned val) {
    for (int i = 0; i < (1 << 18); i++) {
        if (__hip_atomic_load(flag, __ATOMIC_RELAXED, __HIP_MEMORY_SCOPE_SYSTEM) >= val)
            return;
        __builtin_amdgcn_s_sleep(8);
    }
}

__device__ __forceinline__ void pack32(const f32x4 (&v)[2][4], unsigned (&pk)[16]) {
    #pragma unroll
    for (int mt = 0; mt < 2; mt++)
        #pragma unroll
        for (int nt = 0; nt < 4; nt++) {
            pk[(mt * 4 + nt) * 2]     = bfpack2(v[mt][nt][0], v[mt][nt][1]);
            pk[(mt * 4 + nt) * 2 + 1] = bfpack2(v[mt][nt][2], v[mt][nt][3]);
        }
}
// write 32 bf16 (packed bits) into X at this thread's fragment positions
__device__ __forceinline__ void xwrite(bf16* __restrict__ X, const unsigned (&pk)[16],
                                       int mrow, int colBase, int lane) {
    const int lm = lane & 15, lq = lane >> 4;
    #pragma unroll
    for (int mt = 0; mt < 2; mt++)
        #pragma unroll
        for (int nt = 0; nt < 4; nt++) {
            unsigned lo = pk[(mt * 4 + nt) * 2], hi = pk[(mt * 4 + nt) * 2 + 1];
            bf16* xb = X + (mrow + mt * 16 + lq * 4) * P + colBase + nt * 16 + lm;
            xb[0]     = bfraw((unsigned short)(lo & 0xffff));
            xb[P]     = bfraw((unsigned short)(lo >> 16));
            xb[2 * P] = bfraw((unsigned short)(hi & 0xffff));
            xb[3 * P] = bfraw((unsigned short)(hi >> 16));
        }
}

// preload one k-block's 4 weight fragments
__device__ __forceinline__ void loadw4(const bf16* __restrict__ Wp, int k, int woff,
                                       bf16x8 (&w)[4]) {
    const bf16* wp = Wp + (size_t)k * 32768 + woff;
    #pragma unroll
    for (int nt = 0; nt < 4; nt++) w[nt] = *(const bf16x8*)(wp + nt * 512);
}

// ---- 32-row x 64-col GEMM slice (2mt x 4nt), 2-deep weight double-buffer ----
// (r6-proven register footprint; lds pre-offset to the wave's 32-row band)
template<int KB>
__device__ __forceinline__ void gemmW(const bf16* __restrict__ lds,
                                      const bf16* __restrict__ Wp,
                                      int lane, int rot, int woff,
                                      bf16x8 (&wA)[4], f32x4 (&acc)[2][4]) {
    static_assert((KB & (KB - 1)) == 0, "KB must be a power of two");
    const int lm = lane & 15, lq = lane >> 4;
    const bf16* a0b = lds + lm * P + lq * 8;
    const bf16* a1b = a0b + 16 * P;

    bf16x8 wB[4];
    {
        const int k1 = (rot + 1) & (KB - 1);
        const bf16* wp = Wp + (size_t)k1 * 32768 + woff;
        #pragma unroll
        for (int nt = 0; nt < 4; nt++) wB[nt] = *(const bf16x8*)(wp + nt * 512);
    }
    const int k0 = rot & (KB - 1);
    bf16x8 a0 = *(const bf16x8*)(a0b + k0 * 32);
    bf16x8 a1 = *(const bf16x8*)(a1b + k0 * 32);

    #pragma unroll 1
    for (int kb = 0; kb < KB - 2; kb += 2) {
        const int ka1 = (kb + 1 + rot) & (KB - 1);
        const int kw2 = (kb + 2 + rot) & (KB - 1);
        const int kw3 = (kb + 3 + rot) & (KB - 1);
        const bf16* wp2 = Wp + (size_t)kw2 * 32768 + woff;
        const bf16* wp3 = Wp + (size_t)kw3 * 32768 + woff;
        acc[0][0] = mfma16(a0, wA[0], acc[0][0]);
        acc[0][1] = mfma16(a0, wA[1], acc[0][1]);
        acc[0][2] = mfma16(a0, wA[2], acc[0][2]);
        acc[0][3] = mfma16(a0, wA[3], acc[0][3]);
        a0 = *(const bf16x8*)(a0b + ka1 * 32);
        acc[1][0] = mfma16(a1, wA[0], acc[1][0]);
        wA[0] = *(const bf16x8*)(wp2);
        acc[1][1] = mfma16(a1, wA[1], acc[1][1]);
        wA[1] = *(const bf16x8*)(wp2 + 512);
        acc[1][2] = mfma16(a1, wA[2], acc[1][2]);
        wA[2] = *(const bf16x8*)(wp2 + 1024);
        acc[1][3] = mfma16(a1, wA[3], acc[1][3]);
        wA[3] = *(const bf16x8*)(wp2 + 1536);
        a1 = *(const bf16x8*)(a1b + ka1 * 32);
        acc[0][0] = mfma16(a0, wB[0], acc[0][0]);
        acc[0][1] = mfma16(a0, wB[1], acc[0][1]);
        acc[0][2] = mfma16(a0, wB[2], acc[0][2]);
        acc[0][3] = mfma16(a0, wB[3], acc[0][3]);
        a0 = *(const bf16x8*)(a0b + kw2 * 32);
        acc[1][0] = mfma16(a1, wB[0], acc[1][0]);
        wB[0] = *(const bf16x8*)(wp3);
        acc[1][1] = mfma16(a1, wB[1], acc[1][1]);
        wB[1] = *(const bf16x8*)(wp3 + 512);
        acc[1][2] = mfma16(a1, wB[2], acc[1][2]);
        wB[2] = *(const bf16x8*)(wp3 + 1024);
        acc[1][3] = mfma16(a1, wB[3], acc[1][3]);
        wB[3] = *(const bf16x8*)(wp3 + 1536);
        a1 = *(const bf16x8*)(a1b + kw2 * 32);
    }
    {   // peeled last pair: no weight refills
        const int kl = (KB - 1 + rot) & (KB - 1);
        acc[0][0] = mfma16(a0, wA[0], acc[0][0]);
        acc[0][1] = mfma16(a0, wA[1], acc[0][1]);
        acc[0][2] = mfma16(a0, wA[2], acc[0][2]);
        acc[0][3] = mfma16(a0, wA[3], acc[0][3]);
        a0 = *(const bf16x8*)(a0b + kl * 32);
        acc[1][0] = mfma16(a1, wA[0], acc[1][0]);
        acc[1][1] = mfma16(a1, wA[1], acc[1][1]);
        acc[1][2] = mfma16(a1, wA[2], acc[1][2]);
        acc[1][3] = mfma16(a1, wA[3], acc[1][3]);
        a1 = *(const bf16x8*)(a1b + kl * 32);
        acc[0][0] = mfma16(a0, wB[0], acc[0][0]);
        acc[0][1] = mfma16(a0, wB[1], acc[0][1]);
        acc[0][2] = mfma16(a0, wB[2], acc[0][2]);
        acc[0][3] = mfma16(a0, wB[3], acc[0][3]);
        acc[1][0] = mfma16(a1, wB[0], acc[1][0]);
        acc[1][1] = mfma16(a1, wB[1], acc[1][1]);
        acc[1][2] = mfma16(a1, wB[2], acc[1][2]);
        acc[1][3] = mfma16(a1, wB[3], acc[1][3]);
    }
}

// ---------------- persistent fused CDE kernel, XCD column-specialized ----------------
// 256 blocks (1/CU), COOPERATIVE launch (co-residency guarantee for the pair
// handshake; no grid.sync used). Block b: pair p=(b&3)|((b>>3)<<2) (rows p*64..+64),
// side=(b>>2)&1 (cols side*512..+512). side is XCD-UNIFORM under the b%8 dispatch
// map -> each XCD's L2 holds only its 2MiB weight half-set, resident all 50 steps
// (kills the 4MiB at-capacity thrash measured across r1-r9). Pair (b, b^4)
// exchanges z/th halves per step via system-scope stores in d_out (dead until
// epilogue) + per-wave monotone flags; flag couplings bound pair drift to <=1
// phase, which makes the single-buffered exchange regions race-free.
__global__ __launch_bounds__(1024, 4) void cde_main(
    const float* __restrict__ x0,  const float* __restrict__ b_pe, const float* __restrict__ b_hi,
    const float* __restrict__ b1v, const float* __restrict__ b2v,  const float* __restrict__ b_ro,
    const bf16* __restrict__ WpeP, const bf16* __restrict__ WhiP,
    const bf16* __restrict__ W1zP, const bf16* __restrict__ W1uP,
    const bf16* __restrict__ W2P,  const bf16* __restrict__ WroP,
    float* __restrict__ out, unsigned* __restrict__ flags)
{
    extern __shared__ bf16 X[];    // [64][P] staging: g (prologue) / z / th, full 1024 cols

    const int tid  = threadIdx.x;
    const int wave = tid >> 6;
    const int lane = tid & 63;
    const int lm   = lane & 15;
    const int lq   = lane >> 4;
    const int b    = blockIdx.x;
    const int side = (b >> 2) & 1;
    const int pairid = (b & 3) | ((b >> 3) << 2);
    const int rot  = (b >> 3) & 31;            // per-CU k-rotation (r1-best)
    const int cw   = wave >> 1;                // col-wave 0..7
    const int mrow = (wave & 1) * 32;          // row band within the 64 rows
    const int woff = (side * 32 + cw * 4) * 512 + lane * 8;
    const int colOwn = side * 512 + cw * 64;
    const int colPar = (side ^ 1) * 512 + cw * 64;
    const long row0 = (long)pairid * 64;

    // exchange buffers inside the pair's own 256KB out-region (u32 units)
    unsigned* outu = (unsigned*)out;
    unsigned* zW = outu + (size_t)pairid * 65536 + side * 16384 + tid * 16;
    unsigned* zR = outu + (size_t)pairid * 65536 + (side ^ 1) * 16384 + tid * 16;
    unsigned* tW = zW + 32768;
    unsigned* tR = zR + 32768;
    unsigned* zfW = flags + (pairid * 2 + side) * 16 + wave;
    unsigned* zfR = flags + (pairid * 2 + (side ^ 1)) * 16 + wave;
    unsigned* tfW = zfW + 4096;
    unsigned* tfR = zfR + 4096;
    unsigned* ackW = flags + 8192 + (pairid * 2 + side);
    unsigned* ackR = flags + 8192 + (pairid * 2 + (side ^ 1));

    f32x4 z[2][4];        // own half: row mrow+mt*16+lq*4+r, col colOwn+nt*16+lm
    f32x4 g[2][2];        // g: row same, col cw*32+nt*16+lm
    uint2 cu_pk[2][4];

    // ---- prologue: g = x0@W_pe + b_pe ; z(own half) = x0@W_hi + b_hi ----
    #pragma unroll
    for (int nt = 0; nt < 4; nt++) {
        float bh = b_hi[colOwn + nt * 16 + lm];
        #pragma unroll
        for (int r = 0; r < 4; r++) { z[0][nt][r] = bh; z[1][nt][r] = bh; }
    }
    #pragma unroll
    for (int nt = 0; nt < 2; nt++) {
        float bp = b_pe[cw * 32 + nt * 16 + lm];
        #pragma unroll
        for (int r = 0; r < 4; r++) { g[0][nt][r] = bp; g[1][nt][r] = bp; }
    }
    for (int kb = 0; kb < 32; kb++) {
        int kbr = kb + rot; if (kbr >= 32) kbr -= 32;
        bf16x8 a0 = ldcvt8(x0 + (row0 + mrow +      lm) * HID + kbr * 32 + lq * 8);
        bf16x8 a1 = ldcvt8(x0 + (row0 + mrow + 16 + lm) * HID + kbr * 32 + lq * 8);
        const bf16* wp = WhiP + (size_t)kbr * 32768 + woff;
        #pragma unroll
        for (int nt = 0; nt < 4; nt++) {
            bf16x8 bb = *(const bf16x8*)(wp + nt * 512);
            z[0][nt] = mfma16(a0, bb, z[0][nt]);
            z[1][nt] = mfma16(a1, bb, z[1][nt]);
        }
        const bf16* pp = WpeP + (size_t)kbr * 8192 + cw * 1024 + lane * 8;
        #pragma unroll
        for (int nt = 0; nt < 2; nt++) {
            bf16x8 pb = *(const bf16x8*)(pp + nt * 512);
            g[0][nt] = mfma16(a0, pb, g[0][nt]);
            g[1][nt] = mfma16(a1, pb, g[1][nt]);
        }
    }

    // ---- c_u = g @ W1u[:, own half] ----
    #pragma unroll
    for (int mt = 0; mt < 2; mt++)
        #pragma unroll
        for (int nt = 0; nt < 2; nt++)
            #pragma unroll
            for (int r = 0; r < 4; r++)
                X[(mrow + mt * 16 + lq * 4 + r) * P + cw * 32 + nt * 16 + lm] =
                    __float2bfloat16(g[mt][nt][r]);
    __syncthreads();
    {
        f32x4 cu[2][4];
        #pragma unroll
        for (int mt = 0; mt < 2; mt++)
            #pragma unroll
            for (int nt = 0; nt < 4; nt++)
                #pragma unroll
                for (int r = 0; r < 4; r++) cu[mt][nt][r] = 0.0f;
        for (int kb = 0; kb < 8; kb++) {
            const bf16* wp = W1uP + (size_t)kb * 32768 + woff;
            bf16x8 a0 = *(const bf16x8*)(X + (mrow +      lm) * P + kb * 32 + lq * 8);
            bf16x8 a1 = *(const bf16x8*)(X + (mrow + 16 + lm) * P + kb * 32 + lq * 8);
            #pragma unroll
            for (int nt = 0; nt < 4; nt++) {
                bf16x8 bb = *(const bf16x8*)(wp + nt * 512);
                cu[0][nt] = mfma16(a0, bb, cu[0][nt]);
                cu[1][nt] = mfma16(a1, bb, cu[1][nt]);
            }
        }
        #pragma unroll
        for (int mt = 0; mt < 2; mt++)
            #pragma unroll
            for (int nt = 0; nt < 4; nt++)
                cu_pk[mt][nt] = make_uint2(bfpack2(cu[mt][nt][0], cu[mt][nt][1]),
                                           bfpack2(cu[mt][nt][2], cu[mt][nt][3]));
    }
    __syncthreads();   // g-staging reads done before A[0] overwrites X

    const float DT = 1.0f / (float)NSTEP;
    unsigned b12[4];
    #pragma unroll
    for (int nt = 0; nt < 4; nt++)
        b12[nt] = bfpack2(b1v[colOwn + nt * 16 + lm], DT * b2v[colOwn + nt * 16 + lm]);

    bf16x8 wE[4];
    loadw4(W1zP, rot, woff, wE);

    // post initial z for partner's A[0]
    {
        unsigned pk[16]; pack32(z, pk);
        stx16(zW, pk);
        post_wave(zfW, 1u, lane);
    }

    // ---- 50 fused steps ----
    for (int s = 0; s < NSTEP; s++) {
        float t = DT * (float)(s + 1);

        // A: stage own z + partner z into X (partner's post normally already landed)
        {
            unsigned pk[16]; pack32(z, pk);
            xwrite(X, pk, mrow, colOwn, lane);
            spin_wave(zfR, (unsigned)(s + 1));
            unsigned pv[16]; ldx16(pv, zR);
            xwrite(X, pv, mrow, colPar, lane);
        }
        __syncthreads();

        // B: h = z_full @ W1z[:, own] + t*c_u + b1 ; post th early
        f32x4 acc[2][4];
        #pragma unroll
        for (int mt = 0; mt < 2; mt++)
            #pragma unroll
            for (int nt = 0; nt < 4; nt++) {
                float b1 = bflo(b12[nt]);
                unsigned px = cu_pk[mt][nt].x, py = cu_pk[mt][nt].y;
                acc[mt][nt][0] = fmaf(t, bflo(px), b1);
                acc[mt][nt][1] = fmaf(t, bfhi(px), b1);
                acc[mt][nt][2] = fmaf(t, bflo(py), b1);
                acc[mt][nt][3] = fmaf(t, bfhi(py), b1);
            }
        gemmW<32>(X + mrow * P, W1zP, lane, rot, woff, wE, acc);
        loadw4(W2P, rot, woff, wE);
        unsigned tpk[16];
        #pragma unroll
        for (int mt = 0; mt < 2; mt++)
            #pragma unroll
            for (int nt = 0; nt < 4; nt++) {
                acc[mt][nt][0] = DT * tanh_fast(acc[mt][nt][0]);
                acc[mt][nt][1] = DT * tanh_fast(acc[mt][nt][1]);
                acc[mt][nt][2] = DT * tanh_fast(acc[mt][nt][2]);
                acc[mt][nt][3] = DT * tanh_fast(acc[mt][nt][3]);
            }
        pack32(acc, tpk);
        stx16(tW, tpk);
        post_wave(tfW, (unsigned)(s + 1), lane);
        __syncthreads();   // all B-reads of X(z) done

        // T: stage own th + partner th into X
        xwrite(X, tpk, mrow, colOwn, lane);
        spin_wave(tfR, (unsigned)(s + 1));
        {
            unsigned pv[16]; ldx16(pv, tR);
            xwrite(X, pv, mrow, colPar, lane);
        }
        __syncthreads();

        // C: z += dt*b2 ; z += th_full @ W2[:, own] ; post z for partner's A[s+1]
        #pragma unroll
        for (int mt = 0; mt < 2; mt++)
            #pragma unroll
            for (int nt = 0; nt < 4; nt++) {
                float db = bfhi(b12[nt]);
                #pragma unroll
                for (int r = 0; r < 4; r++) z[mt][nt][r] += db;
            }
        gemmW<32>(X + mrow * P, W2P, lane, rot, woff, wE, z);
        if (s + 1 < NSTEP) loadw4(W1zP, rot, woff, wE);
        else               loadw4(WroP, rot, woff, wE);
        {
            unsigned pk[16]; pack32(z, pk);
            stx16(zW, pk);
            post_wave(zfW, (unsigned)(s + 2), lane);
        }
        __syncthreads();   // all C-reads of X(th) done before next A overwrite
    }

    // ---- epilogue: out[:, own half] = z_full @ W_ro[:, own] + b_ro ----
    {
        unsigned pk[16]; pack32(z, pk);
        xwrite(X, pk, mrow, colOwn, lane);
        spin_wave(zfR, (unsigned)(NSTEP + 1));
        unsigned pv[16]; ldx16(pv, zR);
        xwrite(X, pv, mrow, colPar, lane);
    }
    __syncthreads();   // all waves' exchange reads complete
    // ack: partner may clobber the exchange regions with out-stores only after this
    if (tid == 0)
        __hip_atomic_store(ackW, 1u, __ATOMIC_RELEASE, __HIP_MEMORY_SCOPE_SYSTEM);
    {
        f32x4 acc[2][4];
        #pragma unroll
        for (int nt = 0; nt < 4; nt++) {
            float br = b_ro[colOwn + nt * 16 + lm];
            #pragma unroll
            for (int r = 0; r < 4; r++) { acc[0][nt][r] = br; acc[1][nt][r] = br; }
        }
        gemmW<32>(X + mrow * P, WroP, lane, rot, woff, wE, acc);
        spin_wave(ackR, 1u);   // normally long satisfied (one epilogue GEMM of slack)
        #pragma unroll
        for (int mt = 0; mt < 2; mt++)
            #pragma unroll
            for (int nt = 0; nt < 4; nt++)
                #pragma unroll
                for (int r = 0; r < 4; r++)
                    out[(row0 + mrow + mt * 16 + lq * 4 + r) * HID + colOwn + nt * 16 + lm] =
                        acc[mt][nt][r];
    }
}

extern "C" void kernel_launch(void* const* d_in, const int* in_sizes, int n_in,
                              void* d_out, int out_size, void* d_ws, size_t ws_size,
                              hipStream_t stream) {
    (void)in_sizes; (void)n_in; (void)out_size;
    const float* x0  = (const float*)d_in[0];
    const float* Wpe = (const float*)d_in[1];
    const float* bpe = (const float*)d_in[2];
    const float* Whi = (const float*)d_in[3];
    const float* bhi = (const float*)d_in[4];
    const float* W1  = (const float*)d_in[5];
    const float* b1  = (const float*)d_in[6];
    const float* W2  = (const float*)d_in[7];
    const float* b2  = (const float*)d_in[8];
    const float* Wro = (const float*)d_in[9];
    const float* bro = (const float*)d_in[10];

    bf16* ws   = (bf16*)d_ws;
    bf16* WpeP = ws;                          // 256*1024
    bf16* WhiP = WpeP + 256 * 1024;           // 1024*1024
    bf16* W1zP = WhiP + 1024 * 1024;          // 1024*1024 (W1 rows 0..1023)
    bf16* W1uP = W1zP + 1024 * 1024;          // 256*1024  (W1 rows 1024..1279)
    bf16* W2P  = W1uP + 256 * 1024;           // 1024*1024
    bf16* WroP = W2P  + 1024 * 1024;          // 1024*1024  (ends at 9,437,184 B)

    // flags carved from the END of the workspace -> in-bounds by construction
    unsigned* flags = (unsigned*)((char*)d_ws +
                      ((ws_size - (size_t)FLAG_WORDS * 4) & ~(size_t)255));

    hipLaunchKernelGGL(zero_flags, dim3(FLAG_WORDS / 1024), dim3(1024), 0, stream, flags);

    hipLaunchKernelGGL(pack_frag, dim3(1024 / 32, 256 / 16), dim3(64), 0, stream, Wpe, WpeP, 256);
    hipLaunchKernelGGL(pack_frag, dim3(1024 / 32, 1024 / 16), dim3(64), 0, stream, Whi, WhiP, 1024);
    hipLaunchKernelGGL(pack_frag, dim3(1024 / 32, 1024 / 16), dim3(64), 0, stream, W1, W1zP, 1024);
    hipLaunchKernelGGL(pack_frag, dim3(256 / 32, 1024 / 16), dim3(64), 0, stream,
                       W1 + (size_t)1024 * 1024, W1uP, 1024);
    hipLaunchKernelGGL(pack_frag, dim3(1024 / 32, 1024 / 16), dim3(64), 0, stream, W2, W2P, 1024);
    hipLaunchKernelGGL(pack_frag, dim3(1024 / 32, 1024 / 16), dim3(64), 0, stream, Wro, WroP, 1024);

    hipFuncSetAttribute((const void*)cde_main,
                        hipFuncAttributeMaxDynamicSharedMemorySize, SMEM_BYTES);

    const float* outp = (const float*)d_out;
    void* args[] = { (void*)&x0, (void*)&bpe, (void*)&bhi, (void*)&b1, (void*)&b2,
                     (void*)&bro, (void*)&WpeP, (void*)&WhiP, (void*)&W1zP, (void*)&W1uP,
                     (void*)&W2P, (void*)&WroP, (void*)&outp, (void*)&flags };
    hipLaunchCooperativeKernel((const void*)cde_main, dim3(256), dim3(1024),
                               args, SMEM_BYTES, stream);
}

// Round 12
// 2574.274 us; speedup vs baseline: 9.1697x; 9.1697x over previous
//
#include <hip/hip_runtime.h>
#include <hip/hip_bf16.h>

typedef __hip_bfloat16 bf16;
typedef __bf16 bf16x8 __attribute__((ext_vector_type(8)));
typedef float f32x4 __attribute__((ext_vector_type(4)));

#define ROWS   32
#define HID    1024
#define PATH   256
#define NSTEP  50
#define P      1032   // LDS pitch (bf16): r6-best (b128 A-reads; conflicts proven hidden)
#define SMEM_BYTES (2 * ROWS * P * 2)   // inp + th, bf16

__device__ __forceinline__ f32x4 mfma16(bf16x8 a, bf16x8 b, f32x4 c) {
    return __builtin_amdgcn_mfma_f32_16x16x32_bf16(a, b, c, 0, 0, 0);
}

__device__ __forceinline__ float tanh_fast(float x) {
    float e = __expf(2.0f * x);
    return 1.0f - 2.0f / (e + 1.0f);   // saturates, no NaN for finite x
}

__device__ __forceinline__ bf16x8 ldcvt8(const float* __restrict__ p) {
    f32x4 lo = *(const f32x4*)p;
    f32x4 hi = *(const f32x4*)(p + 4);
    bf16x8 r;
    #pragma unroll
    for (int j = 0; j < 4; j++) { r[j] = (__bf16)lo[j]; r[4 + j] = (__bf16)hi[j]; }
    return r;
}

// bf16x2 pack/unpack in a u32 (lo = elem0, hi = elem1)
__device__ __forceinline__ unsigned bfbits(float f) {
    __hip_bfloat16 h = __float2bfloat16(f);
    unsigned short u; __builtin_memcpy(&u, &h, 2);
    return (unsigned)u;
}
__device__ __forceinline__ unsigned bfpack2(float lo, float hi) {
    return bfbits(lo) | (bfbits(hi) << 16);
}
__device__ __forceinline__ float bflo(unsigned u) { return __uint_as_float(u << 16); }
__device__ __forceinline__ float bfhi(unsigned u) { return __uint_as_float(u & 0xffff0000u); }

// ---- pack f32 W[K][N] into bf16 MFMA B-fragment-linear layout ----
// fragment (kb, nb) = 1KB: lane l (lm=l&15, lq=l>>4) holds W[kb*32+lq*8+j][nb*16+lm]
__global__ void pack_frag(const float* __restrict__ src, bf16* __restrict__ dst, int N) {
    int kb = blockIdx.x, nb = blockIdx.y, l = threadIdx.x;
    int lm = l & 15, lq = l >> 4;
    bf16x8 v;
    #pragma unroll
    for (int j = 0; j < 8; j++)
        v[j] = __float2bfloat16(src[(size_t)(kb * 32 + lq * 8 + j) * N + nb * 16 + lm]);
    *(bf16x8*)(dst + ((size_t)(kb * gridDim.y + nb) * 64 + l) * 8) = v;
}

// entry loads for one pass: k-blocks (krot, krot+1) x 2 col-fragments.
// no LDS dependency -> callers hoist these across barriers/compute so their
// latency hides under staging VALU + barrier wait (r12 change).
__device__ __forceinline__ void loadw_entry(const bf16* __restrict__ Wp, int krot,
                                            int nboff, int lane, bf16x8 (&w)[4]) {
    const bf16* b = Wp + nboff + lane * 8;
    const int k1 = (krot + 1) & 31;
    const bf16* p0 = b + (size_t)krot * 32768;
    const bf16* p1 = b + (size_t)k1 * 32768;
    w[0] = *(const bf16x8*)(p0);
    w[1] = *(const bf16x8*)(p0 + 512);
    w[2] = *(const bf16x8*)(p1);
    w[3] = *(const bf16x8*)(p1 + 512);
}

__device__ __forceinline__ void init_acc(float t, float b1, uint2 cu, f32x4& c) {
    c[0] = fmaf(t, bflo(cu.x), b1);
    c[1] = fmaf(t, bfhi(cu.x), b1);
    c[2] = fmaf(t, bflo(cu.y), b1);
    c[3] = fmaf(t, bfhi(cu.y), b1);
}

// ---- 32-row x 32-col GEMM half-pass, 2-k-block-deep weight pipeline ----
// c{mt}{j} += lds_A(32 rows, pitch P) @ Wp cols [nboff-slice, +32); KB k-blocks.
// wE enters holding k-blocks (krot, krot+1); refill distance = 2 k-blocks.
// The nt-SPLIT is the key L2 property (r6/r7 A/B): the whole workgroup sweeps
// (pass0: col-half0, all kb) then (pass1) -> instantaneous cross-XCD weight
// footprint ~1MB/matrix instead of 2MB -> FETCH 3.36 vs 4.28 GB.
template<int KB>
__device__ __forceinline__ void gemm2p(const bf16* __restrict__ lds,
                                       const bf16* __restrict__ Wp,
                                       int lane, int krot, int nboff,
                                       bf16x8 (&wE)[4],
                                       f32x4& c00, f32x4& c01, f32x4& c10, f32x4& c11) {
    static_assert((KB & (KB - 1)) == 0, "KB must be a power of two");
    const int lm = lane & 15, lq = lane >> 4;
    const bf16* a0b = lds + lm * P + lq * 8;
    const bf16* a1b = a0b + 16 * P;
    const bf16* wb = Wp + nboff + lane * 8;

    const int k0 = krot & (KB - 1);
    const int k1 = (krot + 1) & (KB - 1);
    bf16x8 a0A = *(const bf16x8*)(a0b + k0 * 32);
    bf16x8 a1A = *(const bf16x8*)(a1b + k0 * 32);
    bf16x8 a0B = *(const bf16x8*)(a0b + k1 * 32);
    bf16x8 a1B = *(const bf16x8*)(a1b + k1 * 32);

    #pragma unroll 1
    for (int kb = 0; kb < KB - 2; kb += 2) {
        const int kw2 = (kb + 2 + krot) & (KB - 1);
        const int kw3 = (kb + 3 + krot) & (KB - 1);
        const bf16* wp2 = wb + (size_t)kw2 * 32768;
        const bf16* wp3 = wb + (size_t)kw3 * 32768;
        // even: consume (aA, wE[0..1] = kb); refill both <- kb+2
        c00 = mfma16(a0A, wE[0], c00);
        c10 = mfma16(a1A, wE[0], c10);
        wE[0] = *(const bf16x8*)(wp2);
        c01 = mfma16(a0A, wE[1], c01);
        c11 = mfma16(a1A, wE[1], c11);
        wE[1] = *(const bf16x8*)(wp2 + 512);
        a0A = *(const bf16x8*)(a0b + kw2 * 32);
        a1A = *(const bf16x8*)(a1b + kw2 * 32);
        // odd: consume (aB, wE[2..3] = kb+1); refill both <- kb+3
        c00 = mfma16(a0B, wE[2], c00);
        c10 = mfma16(a1B, wE[2], c10);
        wE[2] = *(const bf16x8*)(wp3);
        c01 = mfma16(a0B, wE[3], c01);
        c11 = mfma16(a1B, wE[3], c11);
        wE[3] = *(const bf16x8*)(wp3 + 512);
        a0B = *(const bf16x8*)(a0b + kw3 * 32);
        a1B = *(const bf16x8*)(a1b + kw3 * 32);
    }
    // peeled last pair: no refills
    c00 = mfma16(a0A, wE[0], c00);
    c10 = mfma16(a1A, wE[0], c10);
    c01 = mfma16(a0A, wE[1], c01);
    c11 = mfma16(a1A, wE[1], c11);
    c00 = mfma16(a0B, wE[2], c00);
    c10 = mfma16(a1B, wE[2], c10);
    c01 = mfma16(a0B, wE[3], c01);
    c11 = mfma16(a1B, wE[3], c11);
}

// ---------------- persistent fused CDE kernel ----------------
// 256 wgs (1/CU), 1024 threads = 16 waves. Each wg owns 32 batch rows; z persists
// in f32 registers (MFMA C-layout). Wave w computes cols [64w,64w+64).
// nt-SPLIT (two 32-col passes) for L2 footprint; entry loads hoisted across the
// preceding barrier/compute (r12); k-order wg-uniform rot per CU (r1-best).
__global__ __launch_bounds__(1024, 4) void cde_main(
    const float* __restrict__ x0,  const float* __restrict__ b_pe, const float* __restrict__ b_hi,
    const float* __restrict__ b1v, const float* __restrict__ b2v,  const float* __restrict__ b_ro,
    const bf16* __restrict__ WpeP, const bf16* __restrict__ WhiP,
    const bf16* __restrict__ W1zP, const bf16* __restrict__ W1uP,
    const bf16* __restrict__ W2P,  const bf16* __restrict__ WroP,
    float* __restrict__ out)
{
    extern __shared__ bf16 smem[];
    bf16* inp = smem;              // [32][P]  z staging (cols 0..1023); prologue: g staging
    bf16* th  = smem + ROWS * P;   // [32][P]  dt*tanh staging

    const int tid  = threadIdx.x;
    const int wave = tid >> 6;     // 0..15
    const int lane = tid & 63;
    const int lm   = lane & 15;
    const int lq   = lane >> 4;
    const int rot  = (blockIdx.x >> 3) & 31;   // per-CU spread within an XCD (r1-best)
    const int nb0  = wave * 2048;              // pass0 col-fragment offset (elements)
    const int nb1  = wave * 2048 + 1024;       // pass1
    const long row0 = (long)blockIdx.x * ROWS;

    f32x4 z[2][4];        // row = mt*16+lq*4+r, col = wave*64+nt*16+lm
    f32x4 g[2];           // col = wave*16+lm
    uint2 cu_pk[2][4];    // g @ W1u, packed bf16x2 pairs (r0,r1 | r2,r3)

    // ---- merged prologue: g = x0@W_pe + b_pe ; z = x0@W_hi + b_hi ----
    #pragma unroll
    for (int nt = 0; nt < 4; nt++) {
        float b = b_hi[wave * 64 + nt * 16 + lm];
        #pragma unroll
        for (int r = 0; r < 4; r++) { z[0][nt][r] = b; z[1][nt][r] = b; }
    }
    {
        float b = b_pe[wave * 16 + lm];
        #pragma unroll
        for (int r = 0; r < 4; r++) { g[0][r] = b; g[1][r] = b; }
    }
    for (int kb = 0; kb < HID / 32; kb++) {
        int kbr = kb + rot; if (kbr >= 32) kbr -= 32;
        bf16x8 a0 = ldcvt8(x0 + (row0 +      lm) * HID + kbr * 32 + lq * 8);
        bf16x8 a1 = ldcvt8(x0 + (row0 + 16 + lm) * HID + kbr * 32 + lq * 8);
        const bf16* wp = WhiP + (((size_t)kbr * 64 + wave * 4) * 64 + lane) * 8;
        #pragma unroll
        for (int nt = 0; nt < 4; nt++) {
            bf16x8 bb = *(const bf16x8*)(wp + nt * 512);
            z[0][nt] = mfma16(a0, bb, z[0][nt]);
            z[1][nt] = mfma16(a1, bb, z[1][nt]);
        }
        bf16x8 pb = *(const bf16x8*)(WpeP + (((size_t)kbr * 16 + wave) * 64 + lane) * 8);
        g[0] = mfma16(a0, pb, g[0]);
        g[1] = mfma16(a1, pb, g[1]);
    }

    // ---- c_u = g @ W1u (once), then compress to bf16 pairs ----
    #pragma unroll
    for (int mt = 0; mt < 2; mt++)
        #pragma unroll
        for (int r = 0; r < 4; r++)
            inp[(mt * 16 + lq * 4 + r) * P + wave * 16 + lm] = __float2bfloat16(g[mt][r]);
    __syncthreads();
    {
        f32x4 cu[2][4];
        #pragma unroll
        for (int mt = 0; mt < 2; mt++)
            #pragma unroll
            for (int nt = 0; nt < 4; nt++)
                #pragma unroll
                for (int r = 0; r < 4; r++) cu[mt][nt][r] = 0.0f;
        for (int kb = 0; kb < PATH / 32; kb++) {
            const bf16* wp = W1uP + (((size_t)kb * 64 + wave * 4) * 64 + lane) * 8;
            bf16x8 a0 = *(const bf16x8*)(inp + lm * P + kb * 32 + lq * 8);
            bf16x8 a1 = *(const bf16x8*)(inp + (16 + lm) * P + kb * 32 + lq * 8);
            #pragma unroll
            for (int nt = 0; nt < 4; nt++) {
                bf16x8 bb = *(const bf16x8*)(wp + nt * 512);
                cu[0][nt] = mfma16(a0, bb, cu[0][nt]);
                cu[1][nt] = mfma16(a1, bb, cu[1][nt]);
            }
        }
        #pragma unroll
        for (int mt = 0; mt < 2; mt++)
            #pragma unroll
            for (int nt = 0; nt < 4; nt++)
                cu_pk[mt][nt] = make_uint2(bfpack2(cu[mt][nt][0], cu[mt][nt][1]),
                                           bfpack2(cu[mt][nt][2], cu[mt][nt][3]));
    }
    __syncthreads();

    const float DT = 1.0f / (float)NSTEP;

    // hoisted biases, packed: lo = b1, hi = DT*b2 (bf16 rounding ~5e-5 abs, negligible)
    unsigned b12[4];
    #pragma unroll
    for (int nt = 0; nt < 4; nt++)
        b12[nt] = bfpack2(b1v[wave * 64 + nt * 16 + lm],
                          DT * b2v[wave * 64 + nt * 16 + lm]);

    bf16x8 wE[4], wE2[4];
    loadw_entry(W1zP, rot, nb0, lane, wE);     // first B-pass0 entries, in flight early

    // ---- 50 fused steps ----
    for (int s = 0; s < NSTEP; s++) {
        float t = DT * (float)(s + 1);

        // B-pass1 entries: issued BEFORE the A staging + barrier (latency hides
        // under staging VALU + barrier wait; no LDS dependency) [r12 hoist]
        loadw_entry(W1zP, rot, nb1, lane, wE2);

        // A-phase: refresh bf16 z staging
        #pragma unroll
        for (int mt = 0; mt < 2; mt++)
            #pragma unroll
            for (int nt = 0; nt < 4; nt++)
                #pragma unroll
                for (int r = 0; r < 4; r++)
                    inp[(mt * 16 + lq * 4 + r) * P + wave * 64 + nt * 16 + lm] =
                        __float2bfloat16(z[mt][nt][r]);
        __syncthreads();

        // B pass0: cols [64w, 64w+32)
        {
            f32x4 c00, c01, c10, c11;
            init_acc(t, bflo(b12[0]), cu_pk[0][0], c00);
            init_acc(t, bflo(b12[1]), cu_pk[0][1], c01);
            init_acc(t, bflo(b12[0]), cu_pk[1][0], c10);
            init_acc(t, bflo(b12[1]), cu_pk[1][1], c11);
            gemm2p<HID / 32>(inp, W1zP, lane, rot, nb0, wE, c00, c01, c10, c11);
            loadw_entry(W2P, rot, nb0, lane, wE);  // C-pass0 entries: hide under tanh+pass1
            bf16* tb = th + wave * 64 + lm;
            #pragma unroll
            for (int r = 0; r < 4; r++) {
                tb[(lq * 4 + r) * P]           = __float2bfloat16(DT * tanh_fast(c00[r]));
                tb[(lq * 4 + r) * P + 16]      = __float2bfloat16(DT * tanh_fast(c01[r]));
                tb[(16 + lq * 4 + r) * P]      = __float2bfloat16(DT * tanh_fast(c10[r]));
                tb[(16 + lq * 4 + r) * P + 16] = __float2bfloat16(DT * tanh_fast(c11[r]));
            }
        }
        // B pass1: cols [64w+32, 64w+64)
        {
            f32x4 c00, c01, c10, c11;
            init_acc(t, bflo(b12[2]), cu_pk[0][2], c00);
            init_acc(t, bflo(b12[3]), cu_pk[0][3], c01);
            init_acc(t, bflo(b12[2]), cu_pk[1][2], c10);
            init_acc(t, bflo(b12[3]), cu_pk[1][3], c11);
            gemm2p<HID / 32>(inp, W1zP, lane, rot, nb1, wE2, c00, c01, c10, c11);
            loadw_entry(W2P, rot, nb1, lane, wE2); // C-pass1 entries: hide under tanh+barrier [r12 hoist]
            bf16* tb = th + wave * 64 + 32 + lm;
            #pragma unroll
            for (int r = 0; r < 4; r++) {
                tb[(lq * 4 + r) * P]           = __float2bfloat16(DT * tanh_fast(c00[r]));
                tb[(lq * 4 + r) * P + 16]      = __float2bfloat16(DT * tanh_fast(c01[r]));
                tb[(16 + lq * 4 + r) * P]      = __float2bfloat16(DT * tanh_fast(c10[r]));
                tb[(16 + lq * 4 + r) * P + 16] = __float2bfloat16(DT * tanh_fast(c11[r]));
            }
        }
        __syncthreads();

        // C pass0: z cols 0-1 += dt*b2 ; accumulate (dt*h) @ W2 directly into z
        {
            float d0 = bfhi(b12[0]), d1 = bfhi(b12[1]);
            #pragma unroll
            for (int r = 0; r < 4; r++) {
                z[0][0][r] += d0; z[0][1][r] += d1;
                z[1][0][r] += d0; z[1][1][r] += d1;
            }
            gemm2p<HID / 32>(th, W2P, lane, rot, nb0, wE, z[0][0], z[0][1], z[1][0], z[1][1]);
        }
        // C pass1: z cols 2-3
        {
            float d2 = bfhi(b12[2]), d3 = bfhi(b12[3]);
            #pragma unroll
            for (int r = 0; r < 4; r++) {
                z[0][2][r] += d2; z[0][3][r] += d3;
                z[1][2][r] += d2; z[1][3][r] += d3;
            }
            gemm2p<HID / 32>(th, W2P, lane, rot, nb1, wE2, z[0][2], z[0][3], z[1][2], z[1][3]);
            const bf16* nW = (s + 1 < NSTEP) ? W1zP : WroP;
            loadw_entry(nW, rot, nb0, lane, wE);   // next B-pass0 / epilogue: under A+barrier
        }
        // no barrier: next A-write (inp) is safe — all waves passed the pre-C barrier
        // only after finishing their B-phase inp-reads; th hazards separated by the
        // next loop's post-A barrier.
    }

    // ---- epilogue: out = z @ W_ro + b_ro (f32 store), two passes ----
    loadw_entry(WroP, rot, nb1, lane, wE2);    // hoisted above staging + barrier [r12]
    #pragma unroll
    for (int mt = 0; mt < 2; mt++)
        #pragma unroll
        for (int nt = 0; nt < 4; nt++)
            #pragma unroll
            for (int r = 0; r < 4; r++)
                inp[(mt * 16 + lq * 4 + r) * P + wave * 64 + nt * 16 + lm] =
                    __float2bfloat16(z[mt][nt][r]);
    __syncthreads();
    {
        f32x4 c00, c01, c10, c11;
        float br0 = b_ro[wave * 64 + lm], br1 = b_ro[wave * 64 + 16 + lm];
        #pragma unroll
        for (int r = 0; r < 4; r++) { c00[r] = br0; c01[r] = br1; c10[r] = br0; c11[r] = br1; }
        gemm2p<HID / 32>(inp, WroP, lane, rot, nb0, wE, c00, c01, c10, c11);
        #pragma unroll
        for (int r = 0; r < 4; r++) {
            out[(row0 + lq * 4 + r) * HID + wave * 64 + lm]           = c00[r];
            out[(row0 + lq * 4 + r) * HID + wave * 64 + 16 + lm]      = c01[r];
            out[(row0 + 16 + lq * 4 + r) * HID + wave * 64 + lm]      = c10[r];
            out[(row0 + 16 + lq * 4 + r) * HID + wave * 64 + 16 + lm] = c11[r];
        }
    }
    {
        f32x4 c00, c01, c10, c11;
        float br2 = b_ro[wave * 64 + 32 + lm], br3 = b_ro[wave * 64 + 48 + lm];
        #pragma unroll
        for (int r = 0; r < 4; r++) { c00[r] = br2; c01[r] = br3; c10[r] = br2; c11[r] = br3; }
        gemm2p<HID / 32>(inp, WroP, lane, rot, nb1, wE2, c00, c01, c10, c11);
        #pragma unroll
        for (int r = 0; r < 4; r++) {
            out[(row0 + lq * 4 + r) * HID + wave * 64 + 32 + lm]      = c00[r];
            out[(row0 + lq * 4 + r) * HID + wave * 64 + 48 + lm]      = c01[r];
            out[(row0 + 16 + lq * 4 + r) * HID + wave * 64 + 32 + lm] = c10[r];
            out[(row0 + 16 + lq * 4 + r) * HID + wave * 64 + 48 + lm] = c11[r];
        }
    }
}

extern "C" void kernel_launch(void* const* d_in, const int* in_sizes, int n_in,
                              void* d_out, int out_size, void* d_ws, size_t ws_size,
                              hipStream_t stream) {
    (void)in_sizes; (void)n_in; (void)out_size; (void)ws_size;
    const float* x0  = (const float*)d_in[0];
    const float* Wpe = (const float*)d_in[1];
    const float* bpe = (const float*)d_in[2];
    const float* Whi = (const float*)d_in[3];
    const float* bhi = (const float*)d_in[4];
    const float* W1  = (const float*)d_in[5];
    const float* b1  = (const float*)d_in[6];
    const float* W2  = (const float*)d_in[7];
    const float* b2  = (const float*)d_in[8];
    const float* Wro = (const float*)d_in[9];
    const float* bro = (const float*)d_in[10];

    bf16* ws   = (bf16*)d_ws;
    bf16* WpeP = ws;                          // 256*1024
    bf16* WhiP = WpeP + 256 * 1024;           // 1024*1024
    bf16* W1zP = WhiP + 1024 * 1024;          // 1024*1024 (W1 rows 0..1023)
    bf16* W1uP = W1zP + 1024 * 1024;          // 256*1024  (W1 rows 1024..1279)
    bf16* W2P  = W1uP + 256 * 1024;           // 1024*1024
    bf16* WroP = W2P  + 1024 * 1024;          // 1024*1024

    hipLaunchKernelGGL(pack_frag, dim3(1024 / 32, 256 / 16), dim3(64), 0, stream, Wpe, WpeP, 256);
    hipLaunchKernelGGL(pack_frag, dim3(1024 / 32, 1024 / 16), dim3(64), 0, stream, Whi, WhiP, 1024);
    hipLaunchKernelGGL(pack_frag, dim3(1024 / 32, 1024 / 16), dim3(64), 0, stream, W1, W1zP, 1024);
    hipLaunchKernelGGL(pack_frag, dim3(256 / 32, 1024 / 16), dim3(64), 0, stream,
                       W1 + (size_t)1024 * 1024, W1uP, 1024);
    hipLaunchKernelGGL(pack_frag, dim3(1024 / 32, 1024 / 16), dim3(64), 0, stream, W2, W2P, 1024);
    hipLaunchKernelGGL(pack_frag, dim3(1024 / 32, 1024 / 16), dim3(64), 0, stream, Wro, WroP, 1024);

    hipFuncSetAttribute((const void*)cde_main,
                        hipFuncAttributeMaxDynamicSharedMemorySize, SMEM_BYTES);
    hipLaunchKernelGGL(cde_main, dim3(8192 / ROWS), dim3(1024), SMEM_BYTES, stream,
                       x0, bpe, bhi, b1, b2, bro, WpeP, WhiP, W1zP, W1uP, W2P, WroP,
                       (float*)d_out);
}